// Round 3
// baseline (609.496 us; speedup 1.0000x reference)
//
#include <hip/hip_runtime.h>

// BlockTopK sparsify: per 8-float block of `score`, keep top-4 (stable
// ascending argsort drops the 4 smallest; among equal values the
// earlier-index ones are dropped first), out = x * mask.
//
// Memory-bound streaming kernel. True traffic 805 MB/dispatch; round-1
// measured 175 us/dispatch (4.6 TB/s effective, 73% of 6.3 TB/s ceiling).
// rocprof showed FETCH_SIZE = 256 MiB (not 512): `score` stays resident in
// the 256 MiB Infinity Cache across iterations. This version protects that:
//   - score loads: normal/cached (keep LLC residency)
//   - x loads + out stores: nontemporal (single-use streams, evict-first)
//   - grid-stride loop, 2048 blocks (8 blocks/CU), hand-unrolled x2 for MLP
//
// NOTE: __builtin_nontemporal_* rejects HIP_vector_type (class); use a
// native ext_vector_type(4) float alias for the streamed accesses.
//
// Layout: lane i <-> float4 i (unit-stride, 16B/lane). An 8-float block
// spans a LANE PAIR (2k, 2k+1); half-block scores are exchanged via
// __shfl_xor(.,1) (register-speed cross-lane).

typedef float v4f __attribute__((ext_vector_type(4)));

__device__ __forceinline__ v4f topk_half_block(v4f sv, v4f xv, bool odd) {
    float s[4] = {sv.x, sv.y, sv.z, sv.w};
    float x[4] = {xv.x, xv.y, xv.z, xv.w};

    // Partner lane (lane ^ 1) holds the other half of this 8-block.
    float t[4];
#pragma unroll
    for (int k = 0; k < 4; ++k)
        t[k] = __shfl_xor(s[k], 1);

    // Even lanes own block positions 0..3 (partner holds 4..7).
    // Odd lanes own block positions 4..7 (partner holds 0..3).
    // On a tie with a partner element, the partner's index precedes ours
    // iff we are the odd lane.
    v4f o;
#pragma unroll
    for (int k = 0; k < 4; ++k) {
        int rank = 0;  // # elements strictly before s[k] in stable asc. order
#pragma unroll
        for (int j = 0; j < 4; ++j) {
            if (j != k)
                rank += (s[j] < s[k]) || ((s[j] == s[k]) && (j < k));
            rank += (t[j] < s[k]) || ((t[j] == s[k]) && odd);
        }
        // stable ascending argsort drops the first 4 -> keep iff rank >= 4
        o[k] = (rank >= 4) ? x[k] : 0.0f;
    }
    return o;
}

__global__ __launch_bounds__(256) void sparsify_topk_kernel(
    const v4f* __restrict__ x4,
    const v4f* __restrict__ s4,
    v4f* __restrict__ o4,
    int n4)  // number of float4s = n/4
{
    const bool odd = (threadIdx.x & 1) != 0;
    const int stride = gridDim.x * blockDim.x;

    int i = blockIdx.x * blockDim.x + threadIdx.x;

    // Unroll-by-2: two independent load/compute/store bodies in flight.
    for (; i + stride < n4; i += 2 * stride) {
        const int i0 = i;
        const int i1 = i + stride;

        v4f sv0 = s4[i0];                                // cached: LLC-resident
        v4f sv1 = s4[i1];
        v4f xv0 = __builtin_nontemporal_load(&x4[i0]);   // single-use stream
        v4f xv1 = __builtin_nontemporal_load(&x4[i1]);

        v4f r0 = topk_half_block(sv0, xv0, odd);
        v4f r1 = topk_half_block(sv1, xv1, odd);

        __builtin_nontemporal_store(r0, &o4[i0]);
        __builtin_nontemporal_store(r1, &o4[i1]);
    }
    if (i < n4) {
        v4f sv = s4[i];
        v4f xv = __builtin_nontemporal_load(&x4[i]);
        v4f r  = topk_half_block(sv, xv, odd);
        __builtin_nontemporal_store(r, &o4[i]);
    }
}

extern "C" void kernel_launch(void* const* d_in, const int* in_sizes, int n_in,
                              void* d_out, int out_size, void* d_ws, size_t ws_size,
                              hipStream_t stream) {
    const v4f* x4 = (const v4f*)d_in[0];
    const v4f* s4 = (const v4f*)d_in[1];
    v4f* o4 = (v4f*)d_out;

    int n = in_sizes[0];          // 8192*8192 = 67,108,864 floats
    int n4 = n / 4;               // 16,777,216 float4s

    const int threads = 256;
    // 2048 blocks = 8 blocks/CU x 256 CUs; grid-stride covers the rest.
    // (16 VGPR kernel -> full 32 waves/CU residency.)
    int grid = 2048;
    sparsify_topk_kernel<<<grid, threads, 0, stream>>>(x4, s4, o4, n4);
}

// Round 4
// 576.682 us; speedup vs baseline: 1.0569x; 1.0569x over previous
//
#include <hip/hip_runtime.h>

// BlockTopK sparsify: per 8-float block of `score`, keep top-4 (stable
// ascending argsort drops the 4 smallest; among equal values the
// earlier-index ones are dropped first), out = x * mask.
//
// Memory-bound streaming. True traffic 805 MB/dispatch; score (256 MiB)
// is LLC-resident (FETCH_SIZE shows only 256 MiB), so HBM moves 512 MiB.
// Round-1 (one-shot, 1 chunk/thread): 175 us = 3.07 TB/s HBM.
// Round-3 (grid-stride 2048 + nt): 240 us REGRESSION -> scattered
// cross-wave ordering kills DRAM locality; nt hints changed nothing.
//
// This version: round-1's dense one-shot mapping, but x4 MLP — each block
// owns 4 consecutive 4KB chunks (16KB window); each thread processes
// float4 indices base+t, +256, +512, +768. 8 loads + 4 stores in flight
// per thread, 4x fewer wave launches, cross-wave ordering stays dense.
//
// Layout: lane i <-> float4 i (unit-stride, 16B/lane). An 8-float block
// spans a LANE PAIR (2k, 2k+1); half-block scores exchanged via
// __shfl_xor(.,1) (register-speed cross-lane).

typedef float v4f __attribute__((ext_vector_type(4)));

__device__ __forceinline__ v4f topk_half_block(v4f sv, v4f xv, bool odd) {
    float s[4] = {sv.x, sv.y, sv.z, sv.w};
    float x[4] = {xv.x, xv.y, xv.z, xv.w};

    // Partner lane (lane ^ 1) holds the other half of this 8-block.
    float t[4];
#pragma unroll
    for (int k = 0; k < 4; ++k)
        t[k] = __shfl_xor(s[k], 1);

    // Even lanes own block positions 0..3 (partner holds 4..7).
    // On a tie with a partner element, the partner's index precedes ours
    // iff we are the odd lane.
    v4f o;
#pragma unroll
    for (int k = 0; k < 4; ++k) {
        int rank = 0;  // # elements strictly before s[k] in stable asc. order
#pragma unroll
        for (int j = 0; j < 4; ++j) {
            if (j != k)
                rank += (s[j] < s[k]) || ((s[j] == s[k]) && (j < k));
            rank += (t[j] < s[k]) || ((t[j] == s[k]) && odd);
        }
        // stable ascending argsort drops the first 4 -> keep iff rank >= 4
        o[k] = (rank >= 4) ? x[k] : 0.0f;
    }
    return o;
}

#define CHUNKS 4  // consecutive 4KB chunks per block (256 threads each)

__global__ __launch_bounds__(256) void sparsify_topk_kernel(
    const v4f* __restrict__ x4,
    const v4f* __restrict__ s4,
    v4f* __restrict__ o4,
    int n4)  // number of float4s = n/4
{
    const bool odd = (threadIdx.x & 1) != 0;
    const int base = blockIdx.x * (256 * CHUNKS) + threadIdx.x;

    // n4 (16,777,216) is a multiple of 1024, so no bounds checks needed
    // when grid = n4 / 1024 exactly; keep a guard for safety on the last.
    if (base + 3 * 256 < n4) {
        v4f sv[CHUNKS], xv[CHUNKS];
#pragma unroll
        for (int c = 0; c < CHUNKS; ++c) sv[c] = s4[base + c * 256];
#pragma unroll
        for (int c = 0; c < CHUNKS; ++c) xv[c] = x4[base + c * 256];

        v4f r[CHUNKS];
#pragma unroll
        for (int c = 0; c < CHUNKS; ++c) r[c] = topk_half_block(sv[c], xv[c], odd);

#pragma unroll
        for (int c = 0; c < CHUNKS; ++c) o4[base + c * 256] = r[c];
    } else {
#pragma unroll
        for (int c = 0; c < CHUNKS; ++c) {
            int i = base + c * 256;
            if (i < n4) {
                v4f rv = topk_half_block(s4[i], x4[i], odd);
                o4[i] = rv;
            }
        }
    }
}

extern "C" void kernel_launch(void* const* d_in, const int* in_sizes, int n_in,
                              void* d_out, int out_size, void* d_ws, size_t ws_size,
                              hipStream_t stream) {
    const v4f* x4 = (const v4f*)d_in[0];
    const v4f* s4 = (const v4f*)d_in[1];
    v4f* o4 = (v4f*)d_out;

    int n = in_sizes[0];          // 8192*8192 = 67,108,864 floats
    int n4 = n / 4;               // 16,777,216 float4s

    const int threads = 256;
    const int per_block = threads * CHUNKS;               // 1024 float4s
    int grid = (n4 + per_block - 1) / per_block;          // 16384 blocks
    sparsify_topk_kernel<<<grid, threads, 0, stream>>>(x4, s4, o4, n4);
}